// Round 3
// baseline (209.271 us; speedup 1.0000x reference)
//
#include <hip/hip_runtime.h>

typedef __attribute__((ext_vector_type(8))) short bf16x8;
typedef __attribute__((ext_vector_type(4))) float f32x4;

#define NPTS   40000
#define MOUT   40000
#define EDG    500000
#define FIN    32
#define COUT   64
#define KP     15
#define KFDIM  (KP * FIN)          // 480
#define TM     16                  // output points per block
#define ASTRIDE 488                // bf16 elems; 976B row = 61*16B, 61%8=5 -> conflict-free b128
#define EXTENT 0.6f

__device__ __forceinline__ short f2bf(float x) {
    union { float f; unsigned u; } v; v.f = x;
    unsigned r = (v.u + 0x7fffu + ((v.u >> 16) & 1u)) >> 16;
    return (short)r;
}

// 8 waves/EU: VGPR<=64 (measured exactly 64 in R2), LDS 15.9KB allows 10 blocks
__global__ __launch_bounds__(256, 8) void kpconv_fused(
    const float* __restrict__ points,
    const float* __restrict__ features,
    const float* __restrict__ output_points,
    const int*   __restrict__ nbr_idx,
    const int*   __restrict__ seg_ids,
    const float* __restrict__ k_points,
    const float* __restrict__ k_values,
    float*       __restrict__ out)
{
    __shared__ __align__(16) unsigned short agg[TM * ASTRIDE];  // 15616 B
    __shared__ int seg_start[TM + 1];

    const int tid = threadIdx.x;
    const int m0  = blockIdx.x * TM;

    // ---- segment range binary search (segment_ids is sorted) ----
    if (tid <= TM) {
        const int target = m0 + tid;
        int lo = 0, hi = EDG;
        while (lo < hi) {
            int mid = (lo + hi) >> 1;
            if (seg_ids[mid] < target) lo = mid + 1; else hi = mid;
        }
        seg_start[tid] = lo;
    }
    __syncthreads();

    const int wave = tid >> 6;
    const int lane = tid & 63;
    const int quad = lane >> 4;      // 0..3
    const int l16  = lane & 15;
    const int hi5  = lane >> 5;      // 0 or 1
    const int f    = lane & 31;      // feature channel owned by this lane

    const int myk = lane < KP ? lane : (KP - 1);
    const float kpx = k_points[myk * 3 + 0];
    const float kpy = k_points[myk * 3 + 1];
    const float kpz = k_points[myk * 3 + 2];
    const float inv_ext = 1.f / EXTENT;

    // ---- Phase 1: build agg[m][k*32+f] (bf16) for 4 points per wave ----
    for (int l = wave * 4; l < wave * 4 + 4; ++l) {
        float acc[8];
        #pragma unroll
        for (int j = 0; j < 8; ++j) acc[j] = 0.f;

        const int m  = m0 + l;
        const float ox = output_points[m * 3 + 0];
        const float oy = output_points[m * 3 + 1];
        const float oz = output_points[m * 3 + 2];
        const int e0 = seg_start[l], e1 = seg_start[l + 1];

        int e = e0;
        for (; e + 2 <= e1; e += 2) {
            const int nb0 = nbr_idx[e];
            const int nb1 = nbr_idx[e + 1];
            const float x0 = points[nb0 * 3 + 0] - ox;
            const float y0 = points[nb0 * 3 + 1] - oy;
            const float z0 = points[nb0 * 3 + 2] - oz;
            const float x1 = points[nb1 * 3 + 0] - ox;
            const float y1 = points[nb1 * 3 + 1] - oy;
            const float z1 = points[nb1 * 3 + 2] - oz;
            const float fv0 = features[nb0 * FIN + f];
            const float fv1 = features[nb1 * FIN + f];
            const float dx0 = x0 - kpx, dy0 = y0 - kpy, dz0 = z0 - kpz;
            const float dx1 = x1 - kpx, dy1 = y1 - kpy, dz1 = z1 - kpz;
            const float d20 = dx0 * dx0 + dy0 * dy0 + dz0 * dz0;
            const float d21 = dx1 * dx1 + dy1 * dy1 + dz1 * dz1;
            float w0 = 1.f - sqrtf(d20) * inv_ext; w0 = w0 > 0.f ? w0 : 0.f;
            float w1 = 1.f - sqrtf(d21) * inv_ext; w1 = w1 > 0.f ? w1 : 0.f;
            // j = 0..6: k = 2j+hi5 <= 13+hi5 < 15 always valid
            #pragma unroll
            for (int j = 0; j < 7; ++j) {
                const int k = 2 * j + hi5;
                acc[j] += __shfl(w0, k) * fv0 + __shfl(w1, k) * fv1;
            }
            // j = 7: k = 14+hi5, only valid for hi5 == 0
            {
                const float wk0 = __shfl(w0, 14);
                const float wk1 = __shfl(w1, 14);
                if (!hi5) acc[7] += wk0 * fv0 + wk1 * fv1;
            }
        }
        if (e < e1) {
            const int nb = nbr_idx[e];
            const float rx = points[nb * 3 + 0] - ox;
            const float ry = points[nb * 3 + 1] - oy;
            const float rz = points[nb * 3 + 2] - oz;
            const float fv = features[nb * FIN + f];
            const float dx = rx - kpx, dy = ry - kpy, dz = rz - kpz;
            const float d2 = dx * dx + dy * dy + dz * dz;
            float w = 1.f - sqrtf(d2) * inv_ext; w = w > 0.f ? w : 0.f;
            #pragma unroll
            for (int j = 0; j < 7; ++j) {
                const int k = 2 * j + hi5;
                acc[j] += __shfl(w, k) * fv;
            }
            {
                const float wk = __shfl(w, 14);
                if (!hi5) acc[7] += wk * fv;
            }
        }

        #pragma unroll
        for (int j = 0; j < 8; ++j) {
            const int idx = lane + 64 * j;          // = k*32 + f
            if (idx < KFDIM) agg[l * ASTRIDE + idx] = (unsigned short)f2bf(acc[j]);
        }
    }

    // ---- B-fragment prefetch (W is [480][64] row-major; k*32+f matches) ----
    // Wave w owns output columns 16w..16w+15. B[k][n]: n=lane&15, k=quad*8+j.
    bf16x8 bfr[15];
    const int bcol = wave * 16 + l16;
    #pragma unroll
    for (int s = 0; s < 15; ++s) {
        #pragma unroll
        for (int j = 0; j < 8; ++j)
            bfr[s][j] = f2bf(k_values[(32 * s + quad * 8 + j) * COUT + bcol]);
    }

    __syncthreads();

    // ---- Phase 2: C[16x16] per wave via 15 MFMAs over K=480 ----
    f32x4 c = {0.f, 0.f, 0.f, 0.f};
    #pragma unroll
    for (int s = 0; s < 15; ++s) {
        const bf16x8 af = *(const bf16x8*)&agg[l16 * ASTRIDE + 32 * s + quad * 8];
        c = __builtin_amdgcn_mfma_f32_16x16x32_bf16(af, bfr[s], c, 0, 0, 0);
    }

    // C/D layout: col = lane&15, row = quad*4 + reg
    #pragma unroll
    for (int r = 0; r < 4; ++r) {
        const int row = quad * 4 + r;
        out[(m0 + row) * COUT + wave * 16 + l16] = c[r];
    }
}

extern "C" void kernel_launch(void* const* d_in, const int* in_sizes, int n_in,
                              void* d_out, int out_size, void* d_ws, size_t ws_size,
                              hipStream_t stream) {
    const float* points        = (const float*)d_in[0];
    const float* features      = (const float*)d_in[1];
    const float* output_points = (const float*)d_in[2];
    const int*   nbr_idx       = (const int*)d_in[3];
    const int*   seg_ids       = (const int*)d_in[4];
    const float* k_points      = (const float*)d_in[5];
    const float* k_values      = (const float*)d_in[6];
    float* out = (float*)d_out;

    kpconv_fused<<<MOUT / TM, 256, 0, stream>>>(
        points, features, output_points, nbr_idx, seg_ids,
        k_points, k_values, out);
}

// Round 4
// 157.604 us; speedup vs baseline: 1.3278x; 1.3278x over previous
//
#include <hip/hip_runtime.h>

typedef __attribute__((ext_vector_type(8))) short bf16x8;
typedef __attribute__((ext_vector_type(4))) float f32x4;

#define NPTS   40000
#define MOUT   40000
#define EDG    500000
#define FIN    32
#define COUT   64
#define KP     15
#define KFDIM  (KP * FIN)          // 480
#define TM     16                  // output points per block
#define ASTRIDE 488                // bf16 elems; 976B row = 61*16B -> conflict-free b128
#define EXTENT 0.6f

__device__ __forceinline__ short f2bf(float x) {
    union { float f; unsigned u; } v; v.f = x;
    unsigned r = (v.u + 0x7fffu + ((v.u >> 16) & 1u)) >> 16;
    return (short)r;
}

// (256,4): R2 measured VGPR=64 spill-free at this bound; (256,8) caused
// catastrophic scratch spills (R3: WRITE_SIZE 10->162MB). Do not tighten.
__global__ __launch_bounds__(256, 4) void kpconv_fused(
    const float* __restrict__ points,
    const float* __restrict__ features,
    const float* __restrict__ output_points,
    const int*   __restrict__ nbr_idx,
    const int*   __restrict__ seg_ids,
    const float* __restrict__ k_points,
    const float* __restrict__ k_values,
    float*       __restrict__ out)
{
    __shared__ __align__(16) unsigned short agg[TM * ASTRIDE];  // 15616 B
    __shared__ int seg_start[TM + 1];

    const int tid = threadIdx.x;
    const int m0  = blockIdx.x * TM;

    // ---- segment range binary search (segment_ids is sorted) ----
    if (tid <= TM) {
        const int target = m0 + tid;
        int lo = 0, hi = EDG;
        while (lo < hi) {
            int mid = (lo + hi) >> 1;
            if (seg_ids[mid] < target) lo = mid + 1; else hi = mid;
        }
        seg_start[tid] = lo;
    }
    __syncthreads();

    const int wave = tid >> 6;
    const int lane = tid & 63;
    const int quad = lane >> 4;      // 0..3 (= edge slot in phase 1)
    const int l16  = lane & 15;      // 0..15 (= kernel point in phase 1, 15 idle)
    const int hi5  = lane >> 5;      // 0 or 1
    const int f    = lane & 31;      // feature channel owned by this lane

    // per-lane kernel point (lane's k = l16; k==15 lanes produce w=0)
    const int myk = l16 < KP ? l16 : (KP - 1);
    const float kpx = k_points[myk * 3 + 0];
    const float kpy = k_points[myk * 3 + 1];
    const float kpz = k_points[myk * 3 + 2];
    const float inv_ext = 1.f / EXTENT;

    // ---- Phase 1: 4 edges per wave-step; lane = 16*edge_slot + k ----
    for (int l = wave * 4; l < wave * 4 + 4; ++l) {
        float acc[8];
        #pragma unroll
        for (int j = 0; j < 8; ++j) acc[j] = 0.f;

        const int m  = m0 + l;
        const float ox = output_points[m * 3 + 0];
        const float oy = output_points[m * 3 + 1];
        const float oz = output_points[m * 3 + 2];
        const int e0 = seg_start[l], e1 = seg_start[l + 1];

        for (int e = e0; e < e1; e += 4) {
            const int last = e1 - 1;
            const int c1 = e + 1 < e1 ? e + 1 : last;
            const int c2 = e + 2 < e1 ? e + 2 : last;
            const int c3 = e + 3 < e1 ? e + 3 : last;
            const int nb0 = nbr_idx[e];
            const int nb1 = nbr_idx[c1];
            const int nb2 = nbr_idx[c2];
            const int nb3 = nbr_idx[c3];

            // this lane's own edge for the weight computation
            const int nb_a  = (quad & 1) ? nb1 : nb0;
            const int nb_b  = (quad & 1) ? nb3 : nb2;
            const int nb_own = (quad & 2) ? nb_b : nb_a;
            const float* pp = points + nb_own * 3;
            const float rx = pp[0] - ox;
            const float ry = pp[1] - oy;
            const float rz = pp[2] - oz;
            const float dx = rx - kpx, dy = ry - kpy, dz = rz - kpz;
            const float d2 = dx * dx + dy * dy + dz * dz;
            float w = 1.f - sqrtf(d2) * inv_ext;
            w = w > 0.f ? w : 0.f;
            // kill k==15 lanes and tail edge slots (duplicated clamped edges)
            const int nvalid = e1 - e;
            if (l16 >= KP || quad >= nvalid) w = 0.f;

            // features for all 4 edges at this lane's channel
            const float fv0 = features[nb0 * FIN + f];
            const float fv1 = features[nb1 * FIN + f];
            const float fv2 = features[nb2 * FIN + f];
            const float fv3 = features[nb3 * FIN + f];

            #pragma unroll
            for (int j = 0; j < 8; ++j) {
                const int kj = 2 * j + hi5;          // 0..15; k=15 sources hold w=0
                acc[j] += __shfl(w, kj)      * fv0;
                acc[j] += __shfl(w, 16 + kj) * fv1;
                acc[j] += __shfl(w, 32 + kj) * fv2;
                acc[j] += __shfl(w, 48 + kj) * fv3;
            }
        }

        #pragma unroll
        for (int j = 0; j < 8; ++j) {
            const int idx = lane + 64 * j;          // = k*32 + f
            if (idx < KFDIM) agg[l * ASTRIDE + idx] = (unsigned short)f2bf(acc[j]);
        }
    }

    // ---- B-fragment prefetch (W is [480][64] row-major; k*32+f matches) ----
    // Wave w owns output columns 16w..16w+15. B[k][n]: n=lane&15, k=quad*8+j.
    bf16x8 bfr[15];
    const int bcol = wave * 16 + l16;
    #pragma unroll
    for (int s = 0; s < 15; ++s) {
        #pragma unroll
        for (int j = 0; j < 8; ++j)
            bfr[s][j] = f2bf(k_values[(32 * s + quad * 8 + j) * COUT + bcol]);
    }

    __syncthreads();

    // ---- Phase 2: C[16x16] per wave via 15 MFMAs over K=480 ----
    f32x4 c = {0.f, 0.f, 0.f, 0.f};
    #pragma unroll
    for (int s = 0; s < 15; ++s) {
        const bf16x8 af = *(const bf16x8*)&agg[l16 * ASTRIDE + 32 * s + quad * 8];
        c = __builtin_amdgcn_mfma_f32_16x16x32_bf16(af, bfr[s], c, 0, 0, 0);
    }

    // C/D layout: col = lane&15, row = quad*4 + reg
    #pragma unroll
    for (int r = 0; r < 4; ++r) {
        const int row = quad * 4 + r;
        out[(m0 + row) * COUT + wave * 16 + l16] = c[r];
    }
}

extern "C" void kernel_launch(void* const* d_in, const int* in_sizes, int n_in,
                              void* d_out, int out_size, void* d_ws, size_t ws_size,
                              hipStream_t stream) {
    const float* points        = (const float*)d_in[0];
    const float* features      = (const float*)d_in[1];
    const float* output_points = (const float*)d_in[2];
    const int*   nbr_idx       = (const int*)d_in[3];
    const int*   seg_ids       = (const int*)d_in[4];
    const float* k_points      = (const float*)d_in[5];
    const float* k_values      = (const float*)d_in[6];
    float* out = (float*)d_out;

    kpconv_fused<<<MOUT / TM, 256, 0, stream>>>(
        points, features, output_points, nbr_idx, seg_ids,
        k_points, k_values, out);
}